// Round 11
// baseline (481.135 us; speedup 1.0000x reference)
//
#include <hip/hip_runtime.h>
#include <hip/hip_bf16.h>

#define DHID 128
#define NH 12
#define KDIM 1536   // NH * DHID
#define KSPLIT 3
#define KSL (KDIM / KSPLIT)  // 512
#define BK 64                // k-chunk per LDS stage
#define NCHUNK (KSL / BK)    // 8
#define COMBB 512   // combine_k / bn-stat partial blocks

typedef __attribute__((ext_vector_type(8))) short short8;
typedef __attribute__((ext_vector_type(4))) float f32x4;

static __device__ __forceinline__ unsigned short f2bf(float f) {
  __hip_bfloat16 h = __float2bfloat16(f);
  return __builtin_bit_cast(unsigned short, h);
}
static __device__ __forceinline__ float bf2f(unsigned short u) {
  unsigned v = ((unsigned)u) << 16;
  return __builtin_bit_cast(float, v);
}
// readfirstlane for float: MUST round-trip through int bits (the builtin is
// int(int); passing float directly does a VALUE conversion and corrupts data).
static __device__ __forceinline__ float rfl_f(float x) {
  return __builtin_bit_cast(float, __builtin_amdgcn_readfirstlane(__builtin_bit_cast(int, x)));
}
static __device__ __forceinline__ void gload_lds16(const void* g, void* l) {
  __builtin_amdgcn_global_load_lds(
      (const __attribute__((address_space(1))) unsigned int*)g,
      (__attribute__((address_space(3))) unsigned int*)l, 16, 0, 0);
}

// ---------------- sort (counting sort of edges by dst) ----------------

__global__ void hist_k(const int* __restrict__ dstp, int* __restrict__ cnt, int e0, int et) {
  int e = blockIdx.x * blockDim.x + threadIdx.x;
  if (e >= et) return;
  int d = (e < e0) ? dstp[e] : (e - e0);   // self-loop edges appended at the end
  atomicAdd(&cnt[d], 1);
}

// cnt and cursor may alias (in-place): each element is read before rewrite.
__global__ void scan_k(const int* __restrict__ cnt, int* __restrict__ row_start,
                       int* __restrict__ cursor, int n, int total) {
  __shared__ int part[1024];
  int t = threadIdx.x;
  const int CH = (n + 1023) >> 10;
  int base = t * CH;
  int s = 0;
  for (int j = 0; j < CH; ++j) { int i = base + j; if (i < n) s += cnt[i]; }
  part[t] = s;
  __syncthreads();
  for (int off = 1; off < 1024; off <<= 1) {
    int v = (t >= off) ? part[t - off] : 0;
    __syncthreads();
    part[t] += v;
    __syncthreads();
  }
  int run = (t == 0) ? 0 : part[t - 1];
  for (int j = 0; j < CH; ++j) {
    int i = base + j;
    if (i < n) {
      int c = cnt[i];              // read BEFORE cursor write (may alias)
      row_start[i] = run;
      cursor[i] = run;
      run += c;
    }
  }
  if (t == 0) row_start[n] = total;
}

__global__ void scatter_k(const int* __restrict__ srcp, const int* __restrict__ dstp,
                          int* __restrict__ cursor, int* __restrict__ srcs,
                          int* __restrict__ dsts, int e0, int et) {
  int e = blockIdx.x * blockDim.x + threadIdx.x;
  if (e >= et) return;
  int s = (e < e0) ? srcp[e] : (e - e0);
  int d = (e < e0) ? dstp[e] : (e - e0);
  int pos = atomicAdd(&cursor[d], 1);
  srcs[pos] = s;
  dsts[pos] = d;
}

// ---------------- u_k: (optional BN apply) + bf16 mirror + u = x . Wu[h] ----------------

template<int BN>
__global__ void u_k(const float* __restrict__ in, const float* __restrict__ Wu,
                    const float* __restrict__ sc, const float* __restrict__ sh,
                    unsigned short* __restrict__ xb, float* __restrict__ u, int n) {
  int wid = (blockIdx.x * blockDim.x + threadIdx.x) >> 6;
  if (wid >= n) return;
  int lane = threadIdx.x & 63;
  float2 xv = *(const float2*)(in + (long)wid * DHID + 2 * lane);
  if (BN) {
    float2 scv = *(const float2*)(sc + 2 * lane);
    float2 shv = *(const float2*)(sh + 2 * lane);
    xv.x = xv.x * scv.x + shv.x;
    xv.y = xv.y * scv.y + shv.y;
  }
  unsigned pv = (unsigned)f2bf(xv.x) | ((unsigned)f2bf(xv.y) << 16);
  *(unsigned*)(xb + (long)wid * DHID + 2 * lane) = pv;
  #pragma unroll
  for (int h = 0; h < NH; ++h) {
    float2 wv = *(const float2*)(Wu + h * DHID + 2 * lane);
    float p = xv.x * wv.x + xv.y * wv.y;
    p += __shfl_xor(p, 1);  p += __shfl_xor(p, 2);  p += __shfl_xor(p, 4);
    p += __shfl_xor(p, 8);  p += __shfl_xor(p, 16); p += __shfl_xor(p, 32);
    if (lane == 0) u[wid * NH + h] = p;
  }
}

// ---------------- per-edge attention (thread per edge, dst-sorted order) ----------------

__global__ void att_k(const float* __restrict__ u, const float* __restrict__ cvec,
                      const int* __restrict__ srcs, const int* __restrict__ dsts,
                      const int* __restrict__ row_start, float* __restrict__ attS, int et) {
  int j = blockIdx.x * blockDim.x + threadIdx.x;
  if (j >= et) return;
  int s = srcs[j], d = dsts[j];
  const float4* ud = (const float4*)(u + (long)d * NH);
  const float4* us = (const float4*)(u + (long)s * NH);
  const float4* cp = (const float4*)cvec;
  float w[NH];
  #pragma unroll
  for (int q = 0; q < 3; ++q) {
    float4 a = ud[q], b = us[q], c = cp[q];
    w[4*q+0] = a.x - b.x + c.x;
    w[4*q+1] = a.y - b.y + c.y;
    w[4*q+2] = a.z - b.z + c.z;
    w[4*q+3] = a.w - b.w + c.w;
  }
  float m = w[0];
  #pragma unroll
  for (int h = 1; h < NH; ++h) m = fmaxf(m, w[h]);
  float ssum = 0.f;
  #pragma unroll
  for (int h = 0; h < NH; ++h) { w[h] = __expf(w[h] - m); ssum += w[h]; }
  float deg = (float)(row_start[d + 1] - row_start[d]);
  float inv = 1.f / (ssum * deg);
  float4* op = (float4*)(attS + (long)j * NH);
  #pragma unroll
  for (int q = 0; q < 3; ++q) {
    float4 v;
    v.x = w[4*q+0] * inv; v.y = w[4*q+1] * inv;
    v.z = w[4*q+2] * inv; v.w = w[4*q+3] * inv;
    op[q] = v;
  }
}

// ---------------- edge aggregation: A[n,h,:] = sum_j attS[j,h] * xb[srcs[j]] ----------------
// One node per wave; uniform indices -> scalar loads; attention values moved
// to SGPRs via bitcast readfirstlane. Only the 8 x-gathers are vector loads.

__global__ void edge_k(const unsigned short* __restrict__ xb, const float* __restrict__ attS,
                       const int* __restrict__ srcs, const int* __restrict__ row_start,
                       unsigned short* __restrict__ A, int n) {
  int wid = __builtin_amdgcn_readfirstlane((int)((blockIdx.x * blockDim.x + threadIdx.x) >> 6));
  if (wid >= n) return;
  int lane = threadIdx.x & 63;
  float acc[NH][2];
  #pragma unroll
  for (int h = 0; h < NH; ++h) { acc[h][0] = 0.f; acc[h][1] = 0.f; }
  int beg = __builtin_amdgcn_readfirstlane(row_start[wid]);
  int end = __builtin_amdgcn_readfirstlane(row_start[wid + 1]);
  int j = beg;
  for (; j + 7 < end; j += 8) {
    int sx[8];
    #pragma unroll
    for (int i = 0; i < 8; ++i)
      sx[i] = __builtin_amdgcn_readfirstlane(srcs[j + i]);
    unsigned pv[8];
    #pragma unroll
    for (int i = 0; i < 8; ++i)
      pv[i] = *(const unsigned*)(xb + (long)sx[i] * DHID + 2 * lane);
    #pragma unroll
    for (int i = 0; i < 8; ++i) {
      const float* ap = attS + (long)(j + i) * NH;
      float xv0 = bf2f((unsigned short)pv[i]);
      float xv1 = bf2f((unsigned short)(pv[i] >> 16));
      #pragma unroll
      for (int h = 0; h < NH; ++h) {
        float a = rfl_f(ap[h]);
        acc[h][0] += a * xv0;
        acc[h][1] += a * xv1;
      }
    }
  }
  for (; j < end; ++j) {
    int s0 = __builtin_amdgcn_readfirstlane(srcs[j]);
    unsigned pv = *(const unsigned*)(xb + (long)s0 * DHID + 2 * lane);
    float xv0 = bf2f((unsigned short)pv);
    float xv1 = bf2f((unsigned short)(pv >> 16));
    const float* ap = attS + (long)j * NH;
    #pragma unroll
    for (int h = 0; h < NH; ++h) {
      float a = rfl_f(ap[h]);
      acc[h][0] += a * xv0;
      acc[h][1] += a * xv1;
    }
  }
  unsigned* Ap = (unsigned*)(A + (long)wid * KDIM);
  #pragma unroll
  for (int h = 0; h < NH; ++h) {
    unsigned pv = (unsigned)f2bf(acc[h][0]) | ((unsigned)f2bf(acc[h][1]) << 16);
    Ap[h * (DHID / 2) + lane] = pv;
  }
}

// ---------------- weight repack (all 3 layers): Wcat3[l][c][h*128+k] = Wlin_l[h*128+c][k] ----------------

__global__ void prep_wcat_k(const float* __restrict__ W0, const float* __restrict__ W1,
                            const float* __restrict__ W2, unsigned short* __restrict__ Wcat3) {
  int t = blockIdx.x * blockDim.x + threadIdx.x;  // 3*128*1536 total
  int l = t / (DHID * KDIM), r = t - l * (DHID * KDIM);
  int c = r / KDIM, f = r - c * KDIM;
  int h = f >> 7, k = f & (DHID - 1);
  const float* W = (l == 0) ? W0 : (l == 1) ? W1 : W2;
  Wcat3[t] = f2bf(W[((h << 7) + c) * DHID + k]);
}

// ---------------- GEMM: LDS-staged double-buffered, split-K 3 ----------------

__global__ __launch_bounds__(256) void gemm_k(
    const unsigned short* __restrict__ A, const unsigned short* __restrict__ B,
    float* __restrict__ part, float* __restrict__ outp, int M) {
  __shared__ __align__(16) char smem[2 * 24576];   // 2 buffers x (A 8KB + B 16KB)
  int w = threadIdx.x >> 6, lane = threadIdx.x & 63;
  int lr = lane & 15, lq = lane >> 4;
  int m0 = blockIdx.x * 64, n0 = w * 32;
  int ks = blockIdx.y;
  const long kbeg = (long)ks * KSL;
  f32x4 acc[4][2];
  #pragma unroll
  for (int mf = 0; mf < 4; ++mf)
    #pragma unroll
    for (int nf = 0; nf < 2; ++nf) acc[mf][nf] = (f32x4){0.f, 0.f, 0.f, 0.f};
  const char* Ag = (const char*)A;
  const char* Bg = (const char*)B;

  auto stage = [&](int c, int p) {
    const long kpos = kbeg + (long)c * BK;        // element index
    #pragma unroll
    for (int jj = 0; jj < 2; ++jj) {
      int L = w * 2048 + jj * 1024 + lane * 16;   // linear LDS byte this lane fills
      int r = L >> 7;
      int srcin = (L & 127) ^ ((r & 7) << 4);
      const char* g = Ag + ((long)(m0 + r) * KDIM + kpos) * 2 + srcin;
      gload_lds16(g, &smem[p * 24576 + w * 2048 + jj * 1024]);
    }
    #pragma unroll
    for (int jj = 0; jj < 4; ++jj) {
      int L = w * 4096 + jj * 1024 + lane * 16;
      int r = L >> 7;
      int srcin = (L & 127) ^ ((r & 7) << 4);
      const char* g = Bg + ((long)r * KDIM + kpos) * 2 + srcin;
      gload_lds16(g, &smem[p * 24576 + 8192 + w * 4096 + jj * 1024]);
    }
  };

  auto compute = [&](int p) {
    const char* Ab = &smem[p * 24576];
    const char* Bb = &smem[p * 24576 + 8192];
    #pragma unroll
    for (int kst = 0; kst < 2; ++kst) {
      short8 av[4], bv[2];
      #pragma unroll
      for (int mf = 0; mf < 4; ++mf) {
        int row = mf * 16 + lr;
        int off = row * 128 + ((kst * 64 + lq * 16) ^ ((row & 7) << 4));
        av[mf] = *(const short8*)(Ab + off);
      }
      #pragma unroll
      for (int nf = 0; nf < 2; ++nf) {
        int row = n0 + nf * 16 + lr;
        int off = row * 128 + ((kst * 64 + lq * 16) ^ ((row & 7) << 4));
        bv[nf] = *(const short8*)(Bb + off);
      }
      #pragma unroll
      for (int mf = 0; mf < 4; ++mf)
        #pragma unroll
        for (int nf = 0; nf < 2; ++nf)
          acc[mf][nf] = __builtin_amdgcn_mfma_f32_16x16x32_bf16(av[mf], bv[nf], acc[mf][nf], 0, 0, 0);
    }
  };

  stage(0, 0);
  for (int c = 0; c < NCHUNK; ++c) {
    if (c + 1 < NCHUNK) {
      stage(c + 1, (c + 1) & 1);
      asm volatile("s_waitcnt vmcnt(6)" ::: "memory");  // chunk c's 6 DMAs done; next 6 in flight
    } else {
      asm volatile("s_waitcnt vmcnt(0)" ::: "memory");
    }
    __syncthreads();
    compute(c & 1);
    __syncthreads();
  }

  float* op = (ks == 0) ? outp : (part + (long)(ks - 1) * M * DHID);
  #pragma unroll
  for (int mf = 0; mf < 4; ++mf) {
    #pragma unroll
    for (int nf = 0; nf < 2; ++nf) {
      int c = n0 + nf * 16 + lr;
      int rowb = m0 + mf * 16 + lq * 4;
      #pragma unroll
      for (int r = 0; r < 4; ++r) {
        int row = rowb + r;
        if (row < M) op[(long)row * DHID + c] = acc[mf][nf][r];
      }
    }
  }
}

// ---------------- combine: outp = slice0 + part1 + part2 + bias (+relu), fused BN stats ----------------

template<int RELU, int DOBN>
__global__ __launch_bounds__(256) void combine_k(
    const float* __restrict__ part, const float* __restrict__ bias,
    float* __restrict__ outp, float* __restrict__ bnpart, int M) {
  const int nvec = M * (DHID / 4);
  const int stride = COMBB * 256;
  int t0 = blockIdx.x * 256 + threadIdx.x;
  int c = (t0 & 31) * 4;              // loop-invariant: stride % 32 == 0
  float4 bc = *(const float4*)(bias + c);
  float s0=0,s1=0,s2=0,s3=0,q0=0,q1=0,q2=0,q3=0;
  for (int t = t0; t < nvec; t += stride) {
    long idx = (long)t * 4;
    float4 v  = *(const float4*)(outp + idx);
    float4 p1 = *(const float4*)(part + idx);
    float4 p2 = *(const float4*)(part + (long)M * DHID + idx);
    v.x += p1.x + p2.x + bc.x;
    v.y += p1.y + p2.y + bc.y;
    v.z += p1.z + p2.z + bc.z;
    v.w += p1.w + p2.w + bc.w;
    if (RELU) {
      v.x = fmaxf(v.x, 0.f); v.y = fmaxf(v.y, 0.f);
      v.z = fmaxf(v.z, 0.f); v.w = fmaxf(v.w, 0.f);
    }
    *(float4*)(outp + idx) = v;
    if (DOBN) {
      s0 += v.x; s1 += v.y; s2 += v.z; s3 += v.w;
      q0 += v.x*v.x; q1 += v.y*v.y; q2 += v.z*v.z; q3 += v.w*v.w;
    }
  }
  if (DOBN) {
    s0 += __shfl_xor(s0, 32); s1 += __shfl_xor(s1, 32);
    s2 += __shfl_xor(s2, 32); s3 += __shfl_xor(s3, 32);
    q0 += __shfl_xor(q0, 32); q1 += __shfl_xor(q1, 32);
    q2 += __shfl_xor(q2, 32); q3 += __shfl_xor(q3, 32);
    __shared__ float red[4][256];
    int w = threadIdx.x >> 6, lane = threadIdx.x & 63;
    if (lane < 32) {
      int cb = lane * 4;
      red[w][cb+0] = s0; red[w][cb+1] = s1; red[w][cb+2] = s2; red[w][cb+3] = s3;
      red[w][128+cb+0] = q0; red[w][128+cb+1] = q1; red[w][128+cb+2] = q2; red[w][128+cb+3] = q3;
    }
    __syncthreads();
    int tt = threadIdx.x;
    bnpart[blockIdx.x * 256 + tt] = red[0][tt] + red[1][tt] + red[2][tt] + red[3][tt];
  }
}

// ---------------- BatchNorm finalize ----------------

__global__ void bnfin_k(const float* __restrict__ bnpart,
                        const float* __restrict__ g, const float* __restrict__ b,
                        float* __restrict__ sc, float* __restrict__ sh, float invn) {
  __shared__ float col[256];
  int t = threadIdx.x;
  float s = 0.f;
  #pragma unroll 8
  for (int bb = 0; bb < COMBB; ++bb) s += bnpart[bb * 256 + t];
  col[t] = s;
  __syncthreads();
  if (t < DHID) {
    float m = col[t] * invn;
    float v = col[128 + t] * invn - m * m;
    float rs = rsqrtf(v + 1e-5f);
    float sg = g[t] * rs;
    sc[t] = sg;
    sh[t] = b[t] - m * sg;
  }
}

// ---------------- launch ----------------

extern "C" void kernel_launch(void* const* d_in, const int* in_sizes, int n_in,
                              void* d_out, int out_size, void* d_ws, size_t ws_size,
                              hipStream_t stream) {
  const float* x = (const float*)d_in[0];
  const int* ei = (const int*)d_in[1];
  const int N = in_sizes[0] / DHID;
  const int E0 = in_sizes[1] / 2;
  const int ET = E0 + N;
  const int* srcp = ei;
  const int* dstp = ei + E0;
  const float* Wlin[3] = {(const float*)d_in[2], (const float*)d_in[6], (const float*)d_in[10]};
  const float* Wu[3]   = {(const float*)d_in[3], (const float*)d_in[7], (const float*)d_in[11]};
  const float* cc[3]   = {(const float*)d_in[4], (const float*)d_in[8], (const float*)d_in[12]};
  const float* bb[3]   = {(const float*)d_in[5], (const float*)d_in[9], (const float*)d_in[13]};
  const float* bng[2]  = {(const float*)d_in[14], (const float*)d_in[16]};
  const float* bnb[2]  = {(const float*)d_in[15], (const float*)d_in[17]};

  const int MPAD = ((N + 63) / 64) * 64;

  // carve workspace
  size_t o = 0;
  char* base = (char*)d_ws;
  auto carve = [&](size_t bytes) -> char* {
    char* p = base + o;
    o += (bytes + 255) & ~(size_t)255;
    return p;
  };
  int* row_start = (int*)carve((size_t)(N + 1) * 4);
  int* cursor    = (int*)carve((size_t)N * 4);       // doubles as histogram
  int* srcs      = (int*)carve((size_t)ET * 4);
  int* dsts      = (int*)carve((size_t)ET * 4);
  float* u       = (float*)carve((size_t)N * NH * 4);
  float* bnpart  = (float*)carve((size_t)COMBB * 256 * 4);
  float* bnsc    = (float*)carve((size_t)DHID * 4);
  float* bnsh    = (float*)carve((size_t)DHID * 4);
  unsigned short* Wcat3 = (unsigned short*)carve((size_t)3 * DHID * KDIM * 2);
  float* hA      = (float*)carve((size_t)N * DHID * 4);
  unsigned short* xb = (unsigned short*)carve((size_t)N * DHID * 2);
  unsigned short* A  = (unsigned short*)carve((size_t)MPAD * KDIM * 2);
  size_t attS_bytes = (size_t)ET * NH * 4;
  size_t part_bytes = (size_t)(KSPLIT - 1) * N * DHID * 4;
  char* shared_rg = carve(attS_bytes > part_bytes ? attS_bytes : part_bytes);
  float* attS = (float*)shared_rg;
  float* partb = (float*)shared_rg;
  (void)ws_size; (void)n_in; (void)out_size;

  const int EB = (ET + 255) / 256;
  const int NW = (N + 3) / 4;       // 4 waves (nodes) per 256-thread block
  const int MB64 = (N + 63) / 64;

  // sort edges by dst (once; dst list is layer-invariant) + weight repack (all layers)
  hipMemsetAsync(cursor, 0, (size_t)N * 4, stream);
  hist_k<<<EB, 256, 0, stream>>>(dstp, cursor, E0, ET);
  scan_k<<<1, 1024, 0, stream>>>(cursor, row_start, cursor, N, ET);
  scatter_k<<<EB, 256, 0, stream>>>(srcp, dstp, cursor, srcs, dsts, E0, ET);
  prep_wcat_k<<<(3 * DHID * KDIM) / 256, 256, 0, stream>>>(Wlin[0], Wlin[1], Wlin[2], Wcat3);

  for (int li = 0; li < 3; ++li) {
    const bool last = (li == 2);
    if (li == 0) u_k<0><<<NW, 256, 0, stream>>>(x, Wu[0], bnsc, bnsh, xb, u, N);
    else         u_k<1><<<NW, 256, 0, stream>>>(hA, Wu[li], bnsc, bnsh, xb, u, N);
    att_k<<<EB, 256, 0, stream>>>(u, cc[li], srcs, dsts, row_start, attS, ET);
    edge_k<<<NW, 256, 0, stream>>>(xb, attS, srcs, row_start, A, N);
    float* outp = last ? (float*)d_out : hA;
    gemm_k<<<dim3(MB64, KSPLIT), 256, 0, stream>>>(A, Wcat3 + (size_t)li * DHID * KDIM, partb, outp, N);
    if (!last) {
      combine_k<1, 1><<<COMBB, 256, 0, stream>>>(partb, bb[li], outp, bnpart, N);
      bnfin_k<<<1, 256, 0, stream>>>(bnpart, bng[li], bnb[li], bnsc, bnsh, 1.f / (float)N);
    } else {
      combine_k<0, 0><<<COMBB, 256, 0, stream>>>(partb, bb[li], outp, bnpart, N);
    }
  }
}

// Round 12
// 439.390 us; speedup vs baseline: 1.0950x; 1.0950x over previous
//
#include <hip/hip_runtime.h>
#include <hip/hip_bf16.h>

#define DHID 128
#define NH 12
#define KDIM 1536   // NH * DHID
#define KSPLIT 3
#define KSL (KDIM / KSPLIT)  // 512
#define BK 64                // k-chunk per LDS stage
#define NCHUNK (KSL / BK)    // 8
#define COMBB 512   // combine_k / bn-stat partial blocks

typedef __attribute__((ext_vector_type(8))) short short8;
typedef __attribute__((ext_vector_type(4))) float f32x4;

static __device__ __forceinline__ unsigned short f2bf(float f) {
  __hip_bfloat16 h = __float2bfloat16(f);
  return __builtin_bit_cast(unsigned short, h);
}
static __device__ __forceinline__ float bf2f(unsigned short u) {
  unsigned v = ((unsigned)u) << 16;
  return __builtin_bit_cast(float, v);
}
static __device__ __forceinline__ void gload_lds16(const void* g, void* l) {
  __builtin_amdgcn_global_load_lds(
      (const __attribute__((address_space(1))) unsigned int*)g,
      (__attribute__((address_space(3))) unsigned int*)l, 16, 0, 0);
}

// ---------------- sort (counting sort of edges by dst) ----------------

__global__ void hist_k(const int* __restrict__ dstp, int* __restrict__ cnt, int e0, int et) {
  int e = blockIdx.x * blockDim.x + threadIdx.x;
  if (e >= et) return;
  int d = (e < e0) ? dstp[e] : (e - e0);   // self-loop edges appended at the end
  atomicAdd(&cnt[d], 1);
}

// cnt and cursor may alias (in-place): each element is read before rewrite.
__global__ void scan_k(const int* __restrict__ cnt, int* __restrict__ row_start,
                       int* __restrict__ cursor, int n, int total) {
  __shared__ int part[1024];
  int t = threadIdx.x;
  const int CH = (n + 1023) >> 10;
  int base = t * CH;
  int s = 0;
  for (int j = 0; j < CH; ++j) { int i = base + j; if (i < n) s += cnt[i]; }
  part[t] = s;
  __syncthreads();
  for (int off = 1; off < 1024; off <<= 1) {
    int v = (t >= off) ? part[t - off] : 0;
    __syncthreads();
    part[t] += v;
    __syncthreads();
  }
  int run = (t == 0) ? 0 : part[t - 1];
  for (int j = 0; j < CH; ++j) {
    int i = base + j;
    if (i < n) {
      int c = cnt[i];              // read BEFORE cursor write (may alias)
      row_start[i] = run;
      cursor[i] = run;
      run += c;
    }
  }
  if (t == 0) row_start[n] = total;
}

__global__ void scatter_k(const int* __restrict__ srcp, const int* __restrict__ dstp,
                          int* __restrict__ cursor, int* __restrict__ srcs,
                          int* __restrict__ dsts, int e0, int et) {
  int e = blockIdx.x * blockDim.x + threadIdx.x;
  if (e >= et) return;
  int s = (e < e0) ? srcp[e] : (e - e0);
  int d = (e < e0) ? dstp[e] : (e - e0);
  int pos = atomicAdd(&cursor[d], 1);
  srcs[pos] = s;
  dsts[pos] = d;
}

// ---------------- u_k: (optional BN apply) + bf16 mirror + u = x . Wu[h] ----------------

template<int BN>
__global__ void u_k(const float* __restrict__ in, const float* __restrict__ Wu,
                    const float* __restrict__ sc, const float* __restrict__ sh,
                    unsigned short* __restrict__ xb, float* __restrict__ u, int n) {
  int wid = (blockIdx.x * blockDim.x + threadIdx.x) >> 6;
  if (wid >= n) return;
  int lane = threadIdx.x & 63;
  float2 xv = *(const float2*)(in + (long)wid * DHID + 2 * lane);
  if (BN) {
    float2 scv = *(const float2*)(sc + 2 * lane);
    float2 shv = *(const float2*)(sh + 2 * lane);
    xv.x = xv.x * scv.x + shv.x;
    xv.y = xv.y * scv.y + shv.y;
  }
  unsigned pv = (unsigned)f2bf(xv.x) | ((unsigned)f2bf(xv.y) << 16);
  *(unsigned*)(xb + (long)wid * DHID + 2 * lane) = pv;
  #pragma unroll
  for (int h = 0; h < NH; ++h) {
    float2 wv = *(const float2*)(Wu + h * DHID + 2 * lane);
    float p = xv.x * wv.x + xv.y * wv.y;
    p += __shfl_xor(p, 1);  p += __shfl_xor(p, 2);  p += __shfl_xor(p, 4);
    p += __shfl_xor(p, 8);  p += __shfl_xor(p, 16); p += __shfl_xor(p, 32);
    if (lane == 0) u[wid * NH + h] = p;
  }
}

// ---------------- fused attention + edge aggregation ----------------
// One node per wave. Edges processed in chunks of <=64:
//   Phase A: lane e computes edge e's softmax alone (lane-parallel, no
//            wave redundancy) and stores att[e][0..11] to wave-local LDS.
//   Phase B: whole wave sweeps the chunk; attention comes from broadcast
//            ds_read (same addr, conflict-free), features from bf16 gather.
// Only wave-local sync needed (s_waitcnt lgkmcnt + wave_barrier) - no
// __syncthreads (waves in a block have different trip counts).

__global__ void edge_k(const unsigned short* __restrict__ xb, const float* __restrict__ u,
                       const float* __restrict__ cvec, const int* __restrict__ srcs,
                       const int* __restrict__ row_start, unsigned short* __restrict__ A, int n) {
  __shared__ float attL[4][64][NH];   // 12 KB: per-wave chunk attention
  int w4 = threadIdx.x >> 6;
  int wid = __builtin_amdgcn_readfirstlane((int)(blockIdx.x * 4 + w4));
  if (wid >= n) return;
  int lane = threadIdx.x & 63;
  int beg = __builtin_amdgcn_readfirstlane(row_start[wid]);
  int end = __builtin_amdgcn_readfirstlane(row_start[wid + 1]);
  float invdeg = 1.f / (float)(end - beg);
  // uic[h] = u[wid][h] + c[h]  (wave-uniform)
  float uic[NH];
  {
    const float4* up = (const float4*)(u + (long)wid * NH);
    const float4* cp = (const float4*)cvec;
    #pragma unroll
    for (int q = 0; q < 3; ++q) {
      float4 a = up[q], c = cp[q];
      uic[4*q+0] = a.x + c.x; uic[4*q+1] = a.y + c.y;
      uic[4*q+2] = a.z + c.z; uic[4*q+3] = a.w + c.w;
    }
  }
  float acc[NH][2];
  #pragma unroll
  for (int h = 0; h < NH; ++h) { acc[h][0] = 0.f; acc[h][1] = 0.f; }

  for (int c0 = beg; c0 < end; c0 += 64) {
    int m = end - c0; if (m > 64) m = 64;
    // ---- Phase A: lane-parallel softmax for edges c0..c0+m-1 ----
    if (lane < m) {
      int s = srcs[c0 + lane];
      const float4* usp = (const float4*)(u + (long)s * NH);
      float4 u0 = usp[0], u1 = usp[1], u2 = usp[2];
      float wv[NH];
      wv[0]=uic[0]-u0.x; wv[1]=uic[1]-u0.y; wv[2] =uic[2]-u0.z;  wv[3] =uic[3]-u0.w;
      wv[4]=uic[4]-u1.x; wv[5]=uic[5]-u1.y; wv[6] =uic[6]-u1.z;  wv[7] =uic[7]-u1.w;
      wv[8]=uic[8]-u2.x; wv[9]=uic[9]-u2.y; wv[10]=uic[10]-u2.z; wv[11]=uic[11]-u2.w;
      float mx = wv[0];
      #pragma unroll
      for (int h = 1; h < NH; ++h) mx = fmaxf(mx, wv[h]);
      float ssum = 0.f;
      #pragma unroll
      for (int h = 0; h < NH; ++h) { wv[h] = __expf(wv[h] - mx); ssum += wv[h]; }
      float inv = invdeg / ssum;
      float4* op = (float4*)attL[w4][lane];
      float4 v0, v1, v2;
      v0.x=wv[0]*inv;  v0.y=wv[1]*inv;  v0.z=wv[2]*inv;  v0.w=wv[3]*inv;
      v1.x=wv[4]*inv;  v1.y=wv[5]*inv;  v1.z=wv[6]*inv;  v1.w=wv[7]*inv;
      v2.x=wv[8]*inv;  v2.y=wv[9]*inv;  v2.z=wv[10]*inv; v2.w=wv[11]*inv;
      op[0] = v0; op[1] = v1; op[2] = v2;
    }
    asm volatile("s_waitcnt lgkmcnt(0)" ::: "memory");
    __builtin_amdgcn_wave_barrier();
    // ---- Phase B: wave-wide accumulate over the chunk ----
    int jj = 0;
    for (; jj + 3 < m; jj += 4) {
      int sx[4];
      #pragma unroll
      for (int i = 0; i < 4; ++i)
        sx[i] = __builtin_amdgcn_readfirstlane(srcs[c0 + jj + i]);
      unsigned pv[4];
      #pragma unroll
      for (int i = 0; i < 4; ++i)
        pv[i] = *(const unsigned*)(xb + (long)sx[i] * DHID + 2 * lane);
      #pragma unroll
      for (int i = 0; i < 4; ++i) {
        const float4* ap = (const float4*)attL[w4][jj + i];
        float4 a0 = ap[0], a1 = ap[1], a2 = ap[2];
        float xv0 = bf2f((unsigned short)pv[i]);
        float xv1 = bf2f((unsigned short)(pv[i] >> 16));
        float av[NH];
        av[0]=a0.x; av[1]=a0.y; av[2] =a0.z; av[3] =a0.w;
        av[4]=a1.x; av[5]=a1.y; av[6] =a1.z; av[7] =a1.w;
        av[8]=a2.x; av[9]=a2.y; av[10]=a2.z; av[11]=a2.w;
        #pragma unroll
        for (int h = 0; h < NH; ++h) {
          acc[h][0] += av[h] * xv0;
          acc[h][1] += av[h] * xv1;
        }
      }
    }
    for (; jj < m; ++jj) {
      int s0 = __builtin_amdgcn_readfirstlane(srcs[c0 + jj]);
      unsigned pv = *(const unsigned*)(xb + (long)s0 * DHID + 2 * lane);
      const float4* ap = (const float4*)attL[w4][jj];
      float4 a0 = ap[0], a1 = ap[1], a2 = ap[2];
      float xv0 = bf2f((unsigned short)pv);
      float xv1 = bf2f((unsigned short)(pv >> 16));
      float av[NH];
      av[0]=a0.x; av[1]=a0.y; av[2] =a0.z; av[3] =a0.w;
      av[4]=a1.x; av[5]=a1.y; av[6] =a1.z; av[7] =a1.w;
      av[8]=a2.x; av[9]=a2.y; av[10]=a2.z; av[11]=a2.w;
      #pragma unroll
      for (int h = 0; h < NH; ++h) {
        acc[h][0] += av[h] * xv0;
        acc[h][1] += av[h] * xv1;
      }
    }
    __builtin_amdgcn_wave_barrier();   // keep next chunk's writes behind these reads
  }
  unsigned* Ap = (unsigned*)(A + (long)wid * KDIM);
  #pragma unroll
  for (int h = 0; h < NH; ++h) {
    unsigned pv = (unsigned)f2bf(acc[h][0]) | ((unsigned)f2bf(acc[h][1]) << 16);
    Ap[h * (DHID / 2) + lane] = pv;
  }
}

// ---------------- weight repack (all 3 layers): Wcat3[l][c][h*128+k] = Wlin_l[h*128+c][k] ----------------

__global__ void prep_wcat_k(const float* __restrict__ W0, const float* __restrict__ W1,
                            const float* __restrict__ W2, unsigned short* __restrict__ Wcat3) {
  int t = blockIdx.x * blockDim.x + threadIdx.x;  // 3*128*1536 total
  int l = t / (DHID * KDIM), r = t - l * (DHID * KDIM);
  int c = r / KDIM, f = r - c * KDIM;
  int h = f >> 7, k = f & (DHID - 1);
  const float* W = (l == 0) ? W0 : (l == 1) ? W1 : W2;
  Wcat3[t] = f2bf(W[((h << 7) + c) * DHID + k]);
}

// ---------------- GEMM: LDS-staged double-buffered, split-K 3 ----------------

__global__ __launch_bounds__(256) void gemm_k(
    const unsigned short* __restrict__ A, const unsigned short* __restrict__ B,
    float* __restrict__ part, float* __restrict__ outp, int M) {
  __shared__ __align__(16) char smem[2 * 24576];   // 2 buffers x (A 8KB + B 16KB)
  int w = threadIdx.x >> 6, lane = threadIdx.x & 63;
  int lr = lane & 15, lq = lane >> 4;
  int m0 = blockIdx.x * 64, n0 = w * 32;
  int ks = blockIdx.y;
  const long kbeg = (long)ks * KSL;
  f32x4 acc[4][2];
  #pragma unroll
  for (int mf = 0; mf < 4; ++mf)
    #pragma unroll
    for (int nf = 0; nf < 2; ++nf) acc[mf][nf] = (f32x4){0.f, 0.f, 0.f, 0.f};
  const char* Ag = (const char*)A;
  const char* Bg = (const char*)B;

  auto stage = [&](int c, int p) {
    const long kpos = kbeg + (long)c * BK;        // element index
    #pragma unroll
    for (int jj = 0; jj < 2; ++jj) {
      int L = w * 2048 + jj * 1024 + lane * 16;   // linear LDS byte this lane fills
      int r = L >> 7;
      int srcin = (L & 127) ^ ((r & 7) << 4);
      const char* g = Ag + ((long)(m0 + r) * KDIM + kpos) * 2 + srcin;
      gload_lds16(g, &smem[p * 24576 + w * 2048 + jj * 1024]);
    }
    #pragma unroll
    for (int jj = 0; jj < 4; ++jj) {
      int L = w * 4096 + jj * 1024 + lane * 16;
      int r = L >> 7;
      int srcin = (L & 127) ^ ((r & 7) << 4);
      const char* g = Bg + ((long)r * KDIM + kpos) * 2 + srcin;
      gload_lds16(g, &smem[p * 24576 + 8192 + w * 4096 + jj * 1024]);
    }
  };

  auto compute = [&](int p) {
    const char* Ab = &smem[p * 24576];
    const char* Bb = &smem[p * 24576 + 8192];
    #pragma unroll
    for (int kst = 0; kst < 2; ++kst) {
      short8 av[4], bv[2];
      #pragma unroll
      for (int mf = 0; mf < 4; ++mf) {
        int row = mf * 16 + lr;
        int off = row * 128 + ((kst * 64 + lq * 16) ^ ((row & 7) << 4));
        av[mf] = *(const short8*)(Ab + off);
      }
      #pragma unroll
      for (int nf = 0; nf < 2; ++nf) {
        int row = n0 + nf * 16 + lr;
        int off = row * 128 + ((kst * 64 + lq * 16) ^ ((row & 7) << 4));
        bv[nf] = *(const short8*)(Bb + off);
      }
      #pragma unroll
      for (int mf = 0; mf < 4; ++mf)
        #pragma unroll
        for (int nf = 0; nf < 2; ++nf)
          acc[mf][nf] = __builtin_amdgcn_mfma_f32_16x16x32_bf16(av[mf], bv[nf], acc[mf][nf], 0, 0, 0);
    }
  };

  stage(0, 0);
  for (int c = 0; c < NCHUNK; ++c) {
    if (c + 1 < NCHUNK) {
      stage(c + 1, (c + 1) & 1);
      asm volatile("s_waitcnt vmcnt(6)" ::: "memory");  // chunk c's 6 DMAs done; next 6 in flight
    } else {
      asm volatile("s_waitcnt vmcnt(0)" ::: "memory");
    }
    __syncthreads();
    compute(c & 1);
    __syncthreads();
  }

  float* op = (ks == 0) ? outp : (part + (long)(ks - 1) * M * DHID);
  #pragma unroll
  for (int mf = 0; mf < 4; ++mf) {
    #pragma unroll
    for (int nf = 0; nf < 2; ++nf) {
      int c = n0 + nf * 16 + lr;
      int rowb = m0 + mf * 16 + lq * 4;
      #pragma unroll
      for (int r = 0; r < 4; ++r) {
        int row = rowb + r;
        if (row < M) op[(long)row * DHID + c] = acc[mf][nf][r];
      }
    }
  }
}

// ---------------- combine: outp = slice0 + part1 + part2 + bias (+relu), fused BN stats ----------------

template<int RELU, int DOBN>
__global__ __launch_bounds__(256) void combine_k(
    const float* __restrict__ part, const float* __restrict__ bias,
    float* __restrict__ outp, float* __restrict__ bnpart, int M) {
  const int nvec = M * (DHID / 4);
  const int stride = COMBB * 256;
  int t0 = blockIdx.x * 256 + threadIdx.x;
  int c = (t0 & 31) * 4;              // loop-invariant: stride % 32 == 0
  float4 bc = *(const float4*)(bias + c);
  float s0=0,s1=0,s2=0,s3=0,q0=0,q1=0,q2=0,q3=0;
  for (int t = t0; t < nvec; t += stride) {
    long idx = (long)t * 4;
    float4 v  = *(const float4*)(outp + idx);
    float4 p1 = *(const float4*)(part + idx);
    float4 p2 = *(const float4*)(part + (long)M * DHID + idx);
    v.x += p1.x + p2.x + bc.x;
    v.y += p1.y + p2.y + bc.y;
    v.z += p1.z + p2.z + bc.z;
    v.w += p1.w + p2.w + bc.w;
    if (RELU) {
      v.x = fmaxf(v.x, 0.f); v.y = fmaxf(v.y, 0.f);
      v.z = fmaxf(v.z, 0.f); v.w = fmaxf(v.w, 0.f);
    }
    *(float4*)(outp + idx) = v;
    if (DOBN) {
      s0 += v.x; s1 += v.y; s2 += v.z; s3 += v.w;
      q0 += v.x*v.x; q1 += v.y*v.y; q2 += v.z*v.z; q3 += v.w*v.w;
    }
  }
  if (DOBN) {
    s0 += __shfl_xor(s0, 32); s1 += __shfl_xor(s1, 32);
    s2 += __shfl_xor(s2, 32); s3 += __shfl_xor(s3, 32);
    q0 += __shfl_xor(q0, 32); q1 += __shfl_xor(q1, 32);
    q2 += __shfl_xor(q2, 32); q3 += __shfl_xor(q3, 32);
    __shared__ float red[4][256];
    int w = threadIdx.x >> 6, lane = threadIdx.x & 63;
    if (lane < 32) {
      int cb = lane * 4;
      red[w][cb+0] = s0; red[w][cb+1] = s1; red[w][cb+2] = s2; red[w][cb+3] = s3;
      red[w][128+cb+0] = q0; red[w][128+cb+1] = q1; red[w][128+cb+2] = q2; red[w][128+cb+3] = q3;
    }
    __syncthreads();
    int tt = threadIdx.x;
    bnpart[blockIdx.x * 256 + tt] = red[0][tt] + red[1][tt] + red[2][tt] + red[3][tt];
  }
}

// ---------------- BatchNorm finalize ----------------

__global__ void bnfin_k(const float* __restrict__ bnpart,
                        const float* __restrict__ g, const float* __restrict__ b,
                        float* __restrict__ sc, float* __restrict__ sh, float invn) {
  __shared__ float col[256];
  int t = threadIdx.x;
  float s = 0.f;
  #pragma unroll 8
  for (int bb = 0; bb < COMBB; ++bb) s += bnpart[bb * 256 + t];
  col[t] = s;
  __syncthreads();
  if (t < DHID) {
    float m = col[t] * invn;
    float v = col[128 + t] * invn - m * m;
    float rs = rsqrtf(v + 1e-5f);
    float sg = g[t] * rs;
    sc[t] = sg;
    sh[t] = b[t] - m * sg;
  }
}

// ---------------- launch ----------------

extern "C" void kernel_launch(void* const* d_in, const int* in_sizes, int n_in,
                              void* d_out, int out_size, void* d_ws, size_t ws_size,
                              hipStream_t stream) {
  const float* x = (const float*)d_in[0];
  const int* ei = (const int*)d_in[1];
  const int N = in_sizes[0] / DHID;
  const int E0 = in_sizes[1] / 2;
  const int ET = E0 + N;
  const int* srcp = ei;
  const int* dstp = ei + E0;
  const float* Wlin[3] = {(const float*)d_in[2], (const float*)d_in[6], (const float*)d_in[10]};
  const float* Wu[3]   = {(const float*)d_in[3], (const float*)d_in[7], (const float*)d_in[11]};
  const float* cc[3]   = {(const float*)d_in[4], (const float*)d_in[8], (const float*)d_in[12]};
  const float* bb[3]   = {(const float*)d_in[5], (const float*)d_in[9], (const float*)d_in[13]};
  const float* bng[2]  = {(const float*)d_in[14], (const float*)d_in[16]};
  const float* bnb[2]  = {(const float*)d_in[15], (const float*)d_in[17]};

  const int MPAD = ((N + 63) / 64) * 64;

  // carve workspace
  size_t o = 0;
  char* base = (char*)d_ws;
  auto carve = [&](size_t bytes) -> char* {
    char* p = base + o;
    o += (bytes + 255) & ~(size_t)255;
    return p;
  };
  int* row_start = (int*)carve((size_t)(N + 1) * 4);
  int* cursor    = (int*)carve((size_t)N * 4);       // doubles as histogram
  int* srcs      = (int*)carve((size_t)ET * 4);
  int* dsts      = (int*)carve((size_t)ET * 4);
  float* u       = (float*)carve((size_t)N * NH * 4);
  float* bnpart  = (float*)carve((size_t)COMBB * 256 * 4);
  float* bnsc    = (float*)carve((size_t)DHID * 4);
  float* bnsh    = (float*)carve((size_t)DHID * 4);
  unsigned short* Wcat3 = (unsigned short*)carve((size_t)3 * DHID * KDIM * 2);
  float* hA      = (float*)carve((size_t)N * DHID * 4);
  unsigned short* xb = (unsigned short*)carve((size_t)N * DHID * 2);
  unsigned short* A  = (unsigned short*)carve((size_t)MPAD * KDIM * 2);
  float* partb   = (float*)carve((size_t)(KSPLIT - 1) * N * DHID * 4);
  (void)ws_size; (void)n_in; (void)out_size;

  const int EB = (ET + 255) / 256;
  const int NW = (N + 3) / 4;       // 4 waves (nodes) per 256-thread block
  const int MB64 = (N + 63) / 64;

  // sort edges by dst (once; dst list is layer-invariant) + weight repack (all layers)
  hipMemsetAsync(cursor, 0, (size_t)N * 4, stream);
  hist_k<<<EB, 256, 0, stream>>>(dstp, cursor, E0, ET);
  scan_k<<<1, 1024, 0, stream>>>(cursor, row_start, cursor, N, ET);
  scatter_k<<<EB, 256, 0, stream>>>(srcp, dstp, cursor, srcs, dsts, E0, ET);
  prep_wcat_k<<<(3 * DHID * KDIM) / 256, 256, 0, stream>>>(Wlin[0], Wlin[1], Wlin[2], Wcat3);

  for (int li = 0; li < 3; ++li) {
    const bool last = (li == 2);
    if (li == 0) u_k<0><<<NW, 256, 0, stream>>>(x, Wu[0], bnsc, bnsh, xb, u, N);
    else         u_k<1><<<NW, 256, 0, stream>>>(hA, Wu[li], bnsc, bnsh, xb, u, N);
    edge_k<<<NW, 256, 0, stream>>>(xb, u, cc[li], srcs, row_start, A, N);
    float* outp = last ? (float*)d_out : hA;
    gemm_k<<<dim3(MB64, KSPLIT), 256, 0, stream>>>(A, Wcat3 + (size_t)li * DHID * KDIM, partb, outp, N);
    if (!last) {
      combine_k<1, 1><<<COMBB, 256, 0, stream>>>(partb, bb[li], outp, bnpart, N);
      bnfin_k<<<1, 256, 0, stream>>>(bnpart, bng[li], bnb[li], bnsc, bnsh, 1.f / (float)N);
    } else {
      combine_k<0, 0><<<COMBB, 256, 0, stream>>>(partb, bb[li], outp, bnpart, N);
    }
  }
}